// Round 1
// baseline (3259.987 us; speedup 1.0000x reference)
//
#include <hip/hip_runtime.h>
#include <hip/hip_bf16.h>
#include <cstdint>

#define NTOK 8192
#define NEXP 8
#define HID  2048
#define INTR 5632

typedef float f32x4  __attribute__((ext_vector_type(4)));
typedef short s16x8  __attribute__((ext_vector_type(8)));
typedef short s16x4  __attribute__((ext_vector_type(4)));

__device__ __forceinline__ short bfc(float f) {
  __hip_bfloat16 h = __float2bfloat16(f);
  return __builtin_bit_cast(short, h);
}
__device__ __forceinline__ s16x8 pk8(float4 a, float4 b) {
  s16x8 v;
  v[0]=bfc(a.x); v[1]=bfc(a.y); v[2]=bfc(a.z); v[3]=bfc(a.w);
  v[4]=bfc(b.x); v[5]=bfc(b.y); v[6]=bfc(b.z); v[7]=bfc(b.w);
  return v;
}
__device__ __forceinline__ s16x4 pk4(float4 a) {
  s16x4 v; v[0]=bfc(a.x); v[1]=bfc(a.y); v[2]=bfc(a.z); v[3]=bfc(a.w);
  return v;
}
__device__ __forceinline__ s16x8 cmb(s16x4 a, s16x4 b) {
  s16x8 v;
  v[0]=a[0]; v[1]=a[1]; v[2]=a[2]; v[3]=a[3];
  v[4]=b[0]; v[5]=b[1]; v[6]=b[2]; v[7]=b[3];
  return v;
}

// ds_read_b64_tr_b16: per-lane addr = base + lane*8; quarter-group q reads the
// 128B window at base+q*128 and lane l gets column (l&15) of that 4x16 bf16 tile.
#define TRREAD(dst, addr, IMM) \
  asm volatile("ds_read_b64_tr_b16 %0, %1 offset:" IMM : "=v"(dst) : "v"(addr))

// ---------------- router: logits, softmax, top-2, compaction ----------------
__global__ void router_kernel(const float* __restrict__ x, const float* __restrict__ wr,
                              int* __restrict__ cnt, int* __restrict__ lists,
                              float* __restrict__ wlists) {
  const int wave = threadIdx.x >> 6;
  const int lane = threadIdx.x & 63;
  const int t = blockIdx.x * 4 + wave;
  if (t >= NTOK) return;
  float acc[NEXP];
#pragma unroll
  for (int e = 0; e < NEXP; e++) acc[e] = 0.f;
  const float* xrow = x + (size_t)t * HID;
#pragma unroll
  for (int j = 0; j < HID / 256; j++) {
    const int k = j * 256 + lane * 4;
    float4 xv = *(const float4*)(xrow + k);
#pragma unroll
    for (int e = 0; e < NEXP; e++) {
      float4 wv = *(const float4*)(wr + e * HID + k);
      acc[e] += xv.x * wv.x + xv.y * wv.y + xv.z * wv.z + xv.w * wv.w;
    }
  }
#pragma unroll
  for (int e = 0; e < NEXP; e++) {
    float v = acc[e];
    for (int off = 32; off; off >>= 1) v += __shfl_xor(v, off, 64);
    acc[e] = v;
  }
  if (lane == 0) {
    float m = acc[0];
#pragma unroll
    for (int e = 1; e < NEXP; e++) m = fmaxf(m, acc[e]);
    float p[NEXP], s = 0.f;
#pragma unroll
    for (int e = 0; e < NEXP; e++) { p[e] = __expf(acc[e] - m); s += p[e]; }
    const float inv = 1.f / s;
    int e1 = 0; float b1 = p[0];
#pragma unroll
    for (int e = 1; e < NEXP; e++) if (p[e] > b1) { b1 = p[e]; e1 = e; }
    int e2 = -1; float b2 = -1.f;
#pragma unroll
    for (int e = 0; e < NEXP; e++) if (e != e1 && p[e] > b2) { b2 = p[e]; e2 = e; }
    const int pos1 = atomicAdd(&cnt[e1], 1);
    lists[e1 * NTOK + pos1] = t; wlists[e1 * NTOK + pos1] = b1 * inv;
    const int pos2 = atomicAdd(&cnt[e2], 1);
    lists[e2 * NTOK + pos2] = t; wlists[e2 * NTOK + pos2] = b2 * inv;
  }
}

__global__ void offsets_kernel(const int* __restrict__ cnt, int* __restrict__ offs) {
  if (threadIdx.x == 0 && blockIdx.x == 0) {
    int o = 0;
#pragma unroll
    for (int e = 0; e < NEXP; e++) { offs[e] = o; o += cnt[e]; }
    offs[NEXP] = o;
  }
}

// ---------------- gemm1: h = silu(x@Wg) * (x@Wu), bf16 out ----------------
__global__ __launch_bounds__(256, 2) void gemm1_kernel(
    const float* __restrict__ x, const float* __restrict__ wg,
    const float* __restrict__ wu, const int* __restrict__ cnt,
    const int* __restrict__ offs, const int* __restrict__ lists,
    __hip_bfloat16* __restrict__ hbuf) {
  const int e  = blockIdx.y >> 6;
  const int mt = blockIdx.y & 63;
  const int count = cnt[e];
  if (mt * 128 >= count) return;
  const int n0 = blockIdx.x * 128;
  const int tid = threadIdx.x;
  const int w = tid >> 6, lane = tid & 63;
  const int wm = w >> 1, wn = w & 1;

  __shared__ short Ald[4096];   // 8 subtiles (16r x 32k) in MFMA fragment order
  __shared__ short Bgl[4096];   // 8 nfrags x 8 (4x16) subtiles, tr-read layout
  __shared__ short Bul[4096];

  const int* tl = lists + e * NTOK + mt * 128;
  const int lim = count - mt * 128;
  const int r0 = lane, r1 = lane + 64;
  const int tok0 = (r0 < lim) ? tl[r0] : tl[0];
  const int tok1 = (r1 < lim) ? tl[r1] : tl[0];

  const float* wge = wg + (size_t)e * HID * INTR;
  const float* wue = wu + (size_t)e * HID * INTR;

  const int kk = tid >> 3;            // 0..31 (B row within K-step)
  const int c0 = (tid & 7) * 16;      // B col base
  const int bb = (c0 >> 4) * 512 + (((kk >> 2) & 1) * 4 + (kk >> 3)) * 64 + (kk & 3) * 16;
  const int aoff0 = (r0 >> 4) * 512 + (w * 16 + (r0 & 15)) * 8;
  const int aoff1 = (r1 >> 4) * 512 + (w * 16 + (r1 & 15)) * 8;

  f32x4 accG[4][4], accU[4][4];
#pragma unroll
  for (int i = 0; i < 4; i++)
#pragma unroll
    for (int j = 0; j < 4; j++) {
      accG[i][j] = f32x4{0.f, 0.f, 0.f, 0.f};
      accU[i][j] = f32x4{0.f, 0.f, 0.f, 0.f};
    }

  for (int k0 = 0; k0 < HID; k0 += 32) {
    // global loads (f32) for this K-step
    const float* pa0 = x + (size_t)tok0 * HID + k0 + w * 8;
    const float* pa1 = x + (size_t)tok1 * HID + k0 + w * 8;
    float4 a0 = *(const float4*)pa0, a1 = *(const float4*)(pa0 + 4);
    float4 a2 = *(const float4*)pa1, a3 = *(const float4*)(pa1 + 4);
    const float* pg = wge + (size_t)(k0 + kk) * INTR + n0 + c0;
    const float* pu = wue + (size_t)(k0 + kk) * INTR + n0 + c0;
    float4 g0 = *(const float4*)(pg + 0),  g1 = *(const float4*)(pg + 4);
    float4 g2 = *(const float4*)(pg + 8),  g3 = *(const float4*)(pg + 12);
    float4 u0 = *(const float4*)(pu + 0),  u1 = *(const float4*)(pu + 4);
    float4 u2 = *(const float4*)(pu + 8),  u3 = *(const float4*)(pu + 12);

    *(s16x8*)(Ald + aoff0) = pk8(a0, a1);
    *(s16x8*)(Ald + aoff1) = pk8(a2, a3);
    *(s16x4*)(Bgl + bb + 0)  = pk4(g0);
    *(s16x4*)(Bgl + bb + 4)  = pk4(g1);
    *(s16x4*)(Bgl + bb + 8)  = pk4(g2);
    *(s16x4*)(Bgl + bb + 12) = pk4(g3);
    *(s16x4*)(Bul + bb + 0)  = pk4(u0);
    *(s16x4*)(Bul + bb + 4)  = pk4(u1);
    *(s16x4*)(Bul + bb + 8)  = pk4(u2);
    *(s16x4*)(Bul + bb + 12) = pk4(u3);
    __syncthreads();

    s16x8 af[4];
#pragma unroll
    for (int mf = 0; mf < 4; mf++)
      af[mf] = *(const s16x8*)(Ald + (wm * 4 + mf) * 512 + lane * 8);

    const uint32_t bga = (uint32_t)(uintptr_t)Bgl + wn * 4096 + lane * 8;
    const uint32_t bua = (uint32_t)(uintptr_t)Bul + wn * 4096 + lane * 8;
    s16x4 tg[8], tu[8];
    TRREAD(tg[0], bga, "0");    TRREAD(tg[1], bga, "512");
    TRREAD(tg[2], bga, "1024"); TRREAD(tg[3], bga, "1536");
    TRREAD(tg[4], bga, "2048"); TRREAD(tg[5], bga, "2560");
    TRREAD(tg[6], bga, "3072"); TRREAD(tg[7], bga, "3584");
    TRREAD(tu[0], bua, "0");    TRREAD(tu[1], bua, "512");
    TRREAD(tu[2], bua, "1024"); TRREAD(tu[3], bua, "1536");
    TRREAD(tu[4], bua, "2048"); TRREAD(tu[5], bua, "2560");
    TRREAD(tu[6], bua, "3072"); TRREAD(tu[7], bua, "3584");
    asm volatile("s_waitcnt lgkmcnt(0)" ::: "memory");
    __builtin_amdgcn_sched_barrier(0);

    s16x8 bg[4], bu[4];
#pragma unroll
    for (int nf = 0; nf < 4; nf++) {
      bg[nf] = cmb(tg[2 * nf], tg[2 * nf + 1]);
      bu[nf] = cmb(tu[2 * nf], tu[2 * nf + 1]);
    }
#pragma unroll
    for (int mf = 0; mf < 4; mf++)
#pragma unroll
      for (int nf = 0; nf < 4; nf++) {
        accG[mf][nf] = __builtin_amdgcn_mfma_f32_16x16x32_bf16(af[mf], bg[nf], accG[mf][nf], 0, 0, 0);
        accU[mf][nf] = __builtin_amdgcn_mfma_f32_16x16x32_bf16(af[mf], bu[nf], accU[mf][nf], 0, 0, 0);
      }
    __syncthreads();
  }

  const int hrow0 = offs[e] + mt * 128;
#pragma unroll
  for (int mf = 0; mf < 4; mf++) {
#pragma unroll
    for (int reg = 0; reg < 4; reg++) {
      const int row = wm * 64 + mf * 16 + (lane >> 4) * 4 + reg;
      if (row < lim) {
        __hip_bfloat16* hp = hbuf + (size_t)(hrow0 + row) * INTR + n0 + wn * 64 + (lane & 15);
#pragma unroll
        for (int nf = 0; nf < 4; nf++) {
          const float g = accG[mf][nf][reg];
          const float u = accU[mf][nf][reg];
          const float h = (g / (1.f + __expf(-g))) * u;
          hp[nf * 16] = __float2bfloat16(h);
        }
      }
    }
  }
}

// ---------------- gemm2: out[tok] += (h @ Wd) * w_combine ----------------
__global__ __launch_bounds__(256, 2) void gemm2_kernel(
    const __hip_bfloat16* __restrict__ hbuf, const float* __restrict__ wd,
    const int* __restrict__ cnt, const int* __restrict__ offs,
    const int* __restrict__ lists, const float* __restrict__ wlists,
    float* __restrict__ out) {
  const int e  = blockIdx.y >> 6;
  const int mt = blockIdx.y & 63;
  const int count = cnt[e];
  if (mt * 128 >= count) return;
  const int n0 = blockIdx.x * 128;
  const int tid = threadIdx.x;
  const int w = tid >> 6, lane = tid & 63;
  const int wm = w >> 1, wn = w & 1;

  __shared__ short Ald[4096];
  __shared__ short Bld[4096];

  const int sb = offs[e] + mt * 128;
  const int r0 = lane, r1 = lane + 64;
  int s0 = sb + r0; if (s0 > 2 * NTOK - 1) s0 = 2 * NTOK - 1;
  int s1 = sb + r1; if (s1 > 2 * NTOK - 1) s1 = 2 * NTOK - 1;
  const float* wde = wd + (size_t)e * INTR * HID;
  const short* hb = (const short*)hbuf;

  const int kk = tid >> 3;
  const int c0 = (tid & 7) * 16;
  const int bb = (c0 >> 4) * 512 + (((kk >> 2) & 1) * 4 + (kk >> 3)) * 64 + (kk & 3) * 16;
  const int aoff0 = (r0 >> 4) * 512 + (w * 16 + (r0 & 15)) * 8;
  const int aoff1 = (r1 >> 4) * 512 + (w * 16 + (r1 & 15)) * 8;

  f32x4 acc[4][4];
#pragma unroll
  for (int i = 0; i < 4; i++)
#pragma unroll
    for (int j = 0; j < 4; j++) acc[i][j] = f32x4{0.f, 0.f, 0.f, 0.f};

  for (int k0 = 0; k0 < INTR; k0 += 32) {
    s16x8 av0 = *(const s16x8*)(hb + (size_t)s0 * INTR + k0 + w * 8);
    s16x8 av1 = *(const s16x8*)(hb + (size_t)s1 * INTR + k0 + w * 8);
    const float* pb = wde + (size_t)(k0 + kk) * HID + n0 + c0;
    float4 b0 = *(const float4*)(pb + 0),  b1 = *(const float4*)(pb + 4);
    float4 b2 = *(const float4*)(pb + 8),  b3 = *(const float4*)(pb + 12);

    *(s16x8*)(Ald + aoff0) = av0;
    *(s16x8*)(Ald + aoff1) = av1;
    *(s16x4*)(Bld + bb + 0)  = pk4(b0);
    *(s16x4*)(Bld + bb + 4)  = pk4(b1);
    *(s16x4*)(Bld + bb + 8)  = pk4(b2);
    *(s16x4*)(Bld + bb + 12) = pk4(b3);
    __syncthreads();

    s16x8 af[4];
#pragma unroll
    for (int mf = 0; mf < 4; mf++)
      af[mf] = *(const s16x8*)(Ald + (wm * 4 + mf) * 512 + lane * 8);

    const uint32_t ba = (uint32_t)(uintptr_t)Bld + wn * 4096 + lane * 8;
    s16x4 tb[8];
    TRREAD(tb[0], ba, "0");    TRREAD(tb[1], ba, "512");
    TRREAD(tb[2], ba, "1024"); TRREAD(tb[3], ba, "1536");
    TRREAD(tb[4], ba, "2048"); TRREAD(tb[5], ba, "2560");
    TRREAD(tb[6], ba, "3072"); TRREAD(tb[7], ba, "3584");
    asm volatile("s_waitcnt lgkmcnt(0)" ::: "memory");
    __builtin_amdgcn_sched_barrier(0);

    s16x8 bf[4];
#pragma unroll
    for (int nf = 0; nf < 4; nf++) bf[nf] = cmb(tb[2 * nf], tb[2 * nf + 1]);
#pragma unroll
    for (int mf = 0; mf < 4; mf++)
#pragma unroll
      for (int nf = 0; nf < 4; nf++)
        acc[mf][nf] = __builtin_amdgcn_mfma_f32_16x16x32_bf16(af[mf], bf[nf], acc[mf][nf], 0, 0, 0);
    __syncthreads();
  }

  const int lim = count - mt * 128;
  const int* tle = lists + e * NTOK + mt * 128;
  const float* wle = wlists + e * NTOK + mt * 128;
#pragma unroll
  for (int mf = 0; mf < 4; mf++) {
#pragma unroll
    for (int reg = 0; reg < 4; reg++) {
      const int row = wm * 64 + mf * 16 + (lane >> 4) * 4 + reg;
      if (row < lim) {
        const int tok = tle[row];
        const float wt = wle[row];
        float* op = out + (size_t)tok * HID + n0 + wn * 64 + (lane & 15);
#pragma unroll
        for (int nf = 0; nf < 4; nf++)
          atomicAdd(op + nf * 16, acc[mf][nf][reg] * wt);
      }
    }
  }
}

extern "C" void kernel_launch(void* const* d_in, const int* in_sizes, int n_in,
                              void* d_out, int out_size, void* d_ws, size_t ws_size,
                              hipStream_t stream) {
  const float* x  = (const float*)d_in[0];
  const float* wr = (const float*)d_in[1];
  const float* wg = (const float*)d_in[2];
  const float* wu = (const float*)d_in[3];
  const float* wd = (const float*)d_in[4];
  float* out = (float*)d_out;

  // workspace layout
  int* cnt    = (int*)d_ws;                          // 8 ints
  int* offs   = cnt + 8;                             // 9 ints
  int* lists  = cnt + 32;                            // 8*8192 ints
  float* wlists = (float*)(lists + NEXP * NTOK);     // 8*8192 floats
  __hip_bfloat16* hbuf = (__hip_bfloat16*)((char*)d_ws + (1u << 20));  // 16384 x 5632 bf16

  hipMemsetAsync(cnt, 0, 32 * sizeof(int), stream);
  hipMemsetAsync(out, 0, (size_t)NTOK * HID * sizeof(float), stream);

  router_kernel<<<NTOK / 4, 256, 0, stream>>>(x, wr, cnt, lists, wlists);
  offsets_kernel<<<1, 64, 0, stream>>>(cnt, offs);
  gemm1_kernel<<<dim3(INTR / 128, NEXP * 64), 256, 0, stream>>>(x, wg, wu, cnt, offs, lists, hbuf);
  gemm2_kernel<<<dim3(HID / 128, NEXP * 64), 256, 0, stream>>>(hbuf, wd, cnt, offs, lists, wlists, out);
}

// Round 2
// 2423.460 us; speedup vs baseline: 1.3452x; 1.3452x over previous
//
#include <hip/hip_runtime.h>
#include <hip/hip_bf16.h>
#include <cstdint>

#define NTOK 8192
#define NEXP 8
#define HID  2048
#define INTR 5632
#define NT1  44     // INTR/128 n-tiles for gemm1
#define NT2  16     // HID/128  n-tiles for gemm2
#define MT_MAX 32   // max 256-row m-tiles per expert

typedef float f32x4  __attribute__((ext_vector_type(4)));
typedef short s16x8  __attribute__((ext_vector_type(8)));
typedef short s16x4  __attribute__((ext_vector_type(4)));

__device__ __forceinline__ short bfc(float f) {
  __hip_bfloat16 h = __float2bfloat16(f);
  return __builtin_bit_cast(short, h);
}
__device__ __forceinline__ s16x8 pk8(float4 a, float4 b) {
  s16x8 v;
  v[0]=bfc(a.x); v[1]=bfc(a.y); v[2]=bfc(a.z); v[3]=bfc(a.w);
  v[4]=bfc(b.x); v[5]=bfc(b.y); v[6]=bfc(b.z); v[7]=bfc(b.w);
  return v;
}
__device__ __forceinline__ s16x4 pk4(float4 a) {
  s16x4 v; v[0]=bfc(a.x); v[1]=bfc(a.y); v[2]=bfc(a.z); v[3]=bfc(a.w);
  return v;
}
__device__ __forceinline__ s16x8 cmb(s16x4 a, s16x4 b) {
  s16x8 v;
  v[0]=a[0]; v[1]=a[1]; v[2]=a[2]; v[3]=a[3];
  v[4]=b[0]; v[5]=b[1]; v[6]=b[2]; v[7]=b[3];
  return v;
}
__device__ __forceinline__ void gload16(const void* g, void* l) {
  __builtin_amdgcn_global_load_lds((const __attribute__((address_space(1))) void*)g,
                                   (__attribute__((address_space(3))) void*)l, 16, 0, 0);
}

#define TRREAD(dst, addr, IMM) \
  asm volatile("ds_read_b64_tr_b16 %0, %1 offset:" IMM : "=v"(dst) : "v"(addr))

// ---------------- router: logits, softmax, top-2, compaction, x->bf16 ----------------
__global__ void router_kernel(const float* __restrict__ x, const float* __restrict__ wr,
                              int* __restrict__ cnt, int* __restrict__ lists,
                              float* __restrict__ wlists, __hip_bfloat16* __restrict__ xb) {
  const int wave = threadIdx.x >> 6;
  const int lane = threadIdx.x & 63;
  const int t = blockIdx.x * 4 + wave;
  if (t >= NTOK) return;
  float acc[NEXP];
#pragma unroll
  for (int e = 0; e < NEXP; e++) acc[e] = 0.f;
  const float* xrow = x + (size_t)t * HID;
  short* xbs = (short*)xb + (size_t)t * HID;
#pragma unroll
  for (int j = 0; j < HID / 256; j++) {
    const int k = j * 256 + lane * 4;
    float4 xv = *(const float4*)(xrow + k);
    *(s16x4*)(xbs + k) = pk4(xv);
#pragma unroll
    for (int e = 0; e < NEXP; e++) {
      float4 wv = *(const float4*)(wr + e * HID + k);
      acc[e] += xv.x * wv.x + xv.y * wv.y + xv.z * wv.z + xv.w * wv.w;
    }
  }
#pragma unroll
  for (int e = 0; e < NEXP; e++) {
    float v = acc[e];
    for (int off = 32; off; off >>= 1) v += __shfl_xor(v, off, 64);
    acc[e] = v;
  }
  if (lane == 0) {
    float m = acc[0];
#pragma unroll
    for (int e = 1; e < NEXP; e++) m = fmaxf(m, acc[e]);
    float p[NEXP], s = 0.f;
#pragma unroll
    for (int e = 0; e < NEXP; e++) { p[e] = __expf(acc[e] - m); s += p[e]; }
    const float inv = 1.f / s;
    int e1 = 0; float b1 = p[0];
#pragma unroll
    for (int e = 1; e < NEXP; e++) if (p[e] > b1) { b1 = p[e]; e1 = e; }
    int e2 = -1; float b2 = -1.f;
#pragma unroll
    for (int e = 0; e < NEXP; e++) if (e != e1 && p[e] > b2) { b2 = p[e]; e2 = e; }
    const int pos1 = atomicAdd(&cnt[e1], 1);
    lists[e1 * NTOK + pos1] = t; wlists[e1 * NTOK + pos1] = b1 * inv;
    const int pos2 = atomicAdd(&cnt[e2], 1);
    lists[e2 * NTOK + pos2] = t; wlists[e2 * NTOK + pos2] = b2 * inv;
  }
}

__global__ void offsets_kernel(const int* __restrict__ cnt, int* __restrict__ offs) {
  if (threadIdx.x == 0 && blockIdx.x == 0) {
    int o = 0;
#pragma unroll
    for (int e = 0; e < NEXP; e++) { offs[e] = o; o += cnt[e]; }
    offs[NEXP] = o;
  }
}

// ---------------- gemm1: h = silu(x@Wg) * (x@Wu) -> bf16 ----------------
// 256x128 tile, 512 threads (8 waves = 4M x 2N), BK=32, double-buffered LDS,
// single barrier per K-step, post-issue prefetch. XCD-grouped swizzle: all
// m-tiles of one (e, n-panel) land on one XCD so each weight panel is
// fetched from HBM once and reused via that XCD's L2.
__global__ __launch_bounds__(512, 1) void gemm1_kernel(
    const __hip_bfloat16* __restrict__ xb, const float* __restrict__ wg,
    const float* __restrict__ wu, const int* __restrict__ cnt,
    const int* __restrict__ offs, const int* __restrict__ lists,
    __hip_bfloat16* __restrict__ hbuf) {
  const int P = blockIdx.x;
  const int xcd = P & 7, slot = P >> 3;
  const int mt = slot & 31, jj = slot >> 5;       // jj 0..43
  const int g = jj * 8 + xcd;                     // 0..351 group = (e, n-tile)
  const int e = g / NT1, nt = g % NT1;
  const int count = cnt[e];
  if (mt * 256 >= count) return;
  const int n0 = nt * 128;
  const int lim = count - mt * 256;
  const int tid = threadIdx.x;
  const int w = tid >> 6, lane = tid & 63;
  const int wm = w >> 1, wn = w & 1;

  __shared__ short Ald[2][8192];
  __shared__ short Bgl[2][4096];
  __shared__ short Bul[2][4096];

  const int* tl = lists + e * NTOK + mt * 256;
  const short* xbs = (const short*)xb;
  const short* srcA0; const short* srcA1;
  {
    const int r0 = (w * 2 + 0) * 16 + (lane & 15);
    const int r1 = (w * 2 + 1) * 16 + (lane & 15);
    const int t0 = tl[r0 < lim ? r0 : 0];
    const int t1 = tl[r1 < lim ? r1 : 0];
    srcA0 = xbs + (size_t)t0 * HID + (lane >> 4) * 8;
    srcA1 = xbs + (size_t)t1 * HID + (lane >> 4) * 8;
  }
  const int kk = tid >> 4;            // 0..31 B-row in K-step
  const int c8 = (tid & 15) * 8;      // col base (8 cols/thread)
  const int bb = (c8 >> 4) * 512 + (((kk >> 2) & 1) * 4 + (kk >> 3)) * 64 + (kk & 3) * 16 + (c8 & 15);
  const float* pG = wg + (size_t)e * HID * INTR + (size_t)kk * INTR + n0 + c8;
  const float* pU = wu + (size_t)e * HID * INTR + (size_t)kk * INTR + n0 + c8;

  f32x4 accG[4][4], accU[4][4];
#pragma unroll
  for (int i = 0; i < 4; i++)
#pragma unroll
    for (int j = 0; j < 4; j++) {
      accG[i][j] = f32x4{0.f, 0.f, 0.f, 0.f};
      accU[i][j] = f32x4{0.f, 0.f, 0.f, 0.f};
    }

  // prologue: B(0) into regs, A(0) via global_load_lds into buffer 0
  float4 g0 = ((const float4*)pG)[0], g1 = ((const float4*)pG)[1];
  float4 u0 = ((const float4*)pU)[0], u1 = ((const float4*)pU)[1];
  pG += 32 * (size_t)INTR; pU += 32 * (size_t)INTR;
  gload16(srcA0, &Ald[0][(w * 2 + 0) * 512]);
  gload16(srcA1, &Ald[0][(w * 2 + 1) * 512]);
  srcA0 += 32; srcA1 += 32;

#define G1_BODY(PC, PN, T_)                                                       \
  {                                                                               \
    *(s16x8*)(&Bgl[PC][bb]) = pk8(g0, g1);                                        \
    *(s16x8*)(&Bul[PC][bb]) = pk8(u0, u1);                                        \
    __syncthreads();                                                              \
    s16x8 af[4];                                                                  \
    _Pragma("unroll")                                                             \
    for (int mf = 0; mf < 4; mf++)                                                \
      af[mf] = *(const s16x8*)(&Ald[PC][(wm * 4 + mf) * 512 + lane * 8]);         \
    const uint32_t bga = (uint32_t)(uintptr_t)&Bgl[PC][0] + wn * 4096 + lane * 8; \
    const uint32_t bua = (uint32_t)(uintptr_t)&Bul[PC][0] + wn * 4096 + lane * 8; \
    s16x4 tg[8], tu[8];                                                           \
    TRREAD(tg[0], bga, "0");    TRREAD(tg[1], bga, "512");                        \
    TRREAD(tg[2], bga, "1024"); TRREAD(tg[3], bga, "1536");                       \
    TRREAD(tg[4], bga, "2048"); TRREAD(tg[5], bga, "2560");                       \
    TRREAD(tg[6], bga, "3072"); TRREAD(tg[7], bga, "3584");                       \
    TRREAD(tu[0], bua, "0");    TRREAD(tu[1], bua, "512");                        \
    TRREAD(tu[2], bua, "1024"); TRREAD(tu[3], bua, "1536");                       \
    TRREAD(tu[4], bua, "2048"); TRREAD(tu[5], bua, "2560");                       \
    TRREAD(tu[6], bua, "3072"); TRREAD(tu[7], bua, "3584");                       \
    g0 = ((const float4*)pG)[0]; g1 = ((const float4*)pG)[1];                     \
    u0 = ((const float4*)pU)[0]; u1 = ((const float4*)pU)[1];                     \
    if ((T_) < 62) { pG += 32 * (size_t)INTR; pU += 32 * (size_t)INTR; }          \
    gload16(srcA0, &Ald[PN][(w * 2 + 0) * 512]);                                  \
    gload16(srcA1, &Ald[PN][(w * 2 + 1) * 512]);                                  \
    srcA0 += 32; srcA1 += 32;                                                     \
    asm volatile("s_waitcnt lgkmcnt(0)" ::: "memory");                            \
    __builtin_amdgcn_sched_barrier(0);                                           \
    s16x8 bg[4], bu[4];                                                           \
    _Pragma("unroll")                                                             \
    for (int nf = 0; nf < 4; nf++) {                                              \
      bg[nf] = cmb(tg[2 * nf], tg[2 * nf + 1]);                                   \
      bu[nf] = cmb(tu[2 * nf], tu[2 * nf + 1]);                                   \
    }                                                                             \
    _Pragma("unroll")                                                             \
    for (int mf = 0; mf < 4; mf++)                                                \
      _Pragma("unroll")                                                           \
      for (int nf = 0; nf < 4; nf++) {                                            \
        accG[mf][nf] = __builtin_amdgcn_mfma_f32_16x16x32_bf16(af[mf], bg[nf], accG[mf][nf], 0, 0, 0); \
        accU[mf][nf] = __builtin_amdgcn_mfma_f32_16x16x32_bf16(af[mf], bu[nf], accU[mf][nf], 0, 0, 0); \
      }                                                                           \
  }

  for (int t = 0; t < 64; t += 2) {
    G1_BODY(0, 1, t)
    G1_BODY(1, 0, t + 1)
  }
#undef G1_BODY

  const int hrow0 = offs[e] + mt * 256;
#pragma unroll
  for (int mf = 0; mf < 4; mf++) {
#pragma unroll
    for (int reg = 0; reg < 4; reg++) {
      const int row = wm * 64 + mf * 16 + (lane >> 4) * 4 + reg;
      if (row < lim) {
        __hip_bfloat16* hp = hbuf + (size_t)(hrow0 + row) * INTR + n0 + wn * 64 + (lane & 15);
#pragma unroll
        for (int nf = 0; nf < 4; nf++) {
          const float gv = accG[mf][nf][reg];
          const float uv = accU[mf][nf][reg];
          const float h = (gv / (1.f + __expf(-gv))) * uv;
          hp[nf * 16] = __float2bfloat16(h);
        }
      }
    }
  }
}

// ---------------- gemm2: out[tok] += (h @ Wd) * w_combine ----------------
__global__ __launch_bounds__(512, 1) void gemm2_kernel(
    const __hip_bfloat16* __restrict__ hbuf, const float* __restrict__ wd,
    const int* __restrict__ cnt, const int* __restrict__ offs,
    const int* __restrict__ lists, const float* __restrict__ wlists,
    float* __restrict__ out) {
  const int P = blockIdx.x;
  const int xcd = P & 7, slot = P >> 3;
  const int mt = slot & 31, jj = slot >> 5;       // jj 0..15
  const int g = jj * 8 + xcd;                     // 0..127
  const int e = g >> 4, nt = g & 15;
  const int count = cnt[e];
  if (mt * 256 >= count) return;
  const int n0 = nt * 128;
  const int lim = count - mt * 256;
  const int tid = threadIdx.x;
  const int w = tid >> 6, lane = tid & 63;
  const int wm = w >> 1, wn = w & 1;

  __shared__ short Ald[2][8192];
  __shared__ short Bld[2][4096];

  const int sb = offs[e] + mt * 256;
  const short* hb = (const short*)hbuf;
  const short* srcA0; const short* srcA1;
  {
    int s0 = sb + (w * 2 + 0) * 16 + (lane & 15);
    int s1 = sb + (w * 2 + 1) * 16 + (lane & 15);
    if (s0 > 2 * NTOK - 1) s0 = 2 * NTOK - 1;
    if (s1 > 2 * NTOK - 1) s1 = 2 * NTOK - 1;
    srcA0 = hb + (size_t)s0 * INTR + (lane >> 4) * 8;
    srcA1 = hb + (size_t)s1 * INTR + (lane >> 4) * 8;
  }
  const int kk = tid >> 4;
  const int c8 = (tid & 15) * 8;
  const int bb = (c8 >> 4) * 512 + (((kk >> 2) & 1) * 4 + (kk >> 3)) * 64 + (kk & 3) * 16 + (c8 & 15);
  const float* pB = wd + (size_t)e * INTR * HID + (size_t)kk * HID + n0 + c8;

  f32x4 acc[4][4];
#pragma unroll
  for (int i = 0; i < 4; i++)
#pragma unroll
    for (int j = 0; j < 4; j++) acc[i][j] = f32x4{0.f, 0.f, 0.f, 0.f};

  float4 b0 = ((const float4*)pB)[0], b1 = ((const float4*)pB)[1];
  pB += 32 * (size_t)HID;
  gload16(srcA0, &Ald[0][(w * 2 + 0) * 512]);
  gload16(srcA1, &Ald[0][(w * 2 + 1) * 512]);
  srcA0 += 32; srcA1 += 32;

#define G2_BODY(PC, PN, T_)                                                       \
  {                                                                               \
    *(s16x8*)(&Bld[PC][bb]) = pk8(b0, b1);                                        \
    __syncthreads();                                                              \
    s16x8 af[4];                                                                  \
    _Pragma("unroll")                                                             \
    for (int mf = 0; mf < 4; mf++)                                                \
      af[mf] = *(const s16x8*)(&Ald[PC][(wm * 4 + mf) * 512 + lane * 8]);         \
    const uint32_t ba = (uint32_t)(uintptr_t)&Bld[PC][0] + wn * 4096 + lane * 8;  \
    s16x4 tb[8];                                                                  \
    TRREAD(tb[0], ba, "0");    TRREAD(tb[1], ba, "512");                          \
    TRREAD(tb[2], ba, "1024"); TRREAD(tb[3], ba, "1536");                         \
    TRREAD(tb[4], ba, "2048"); TRREAD(tb[5], ba, "2560");                         \
    TRREAD(tb[6], ba, "3072"); TRREAD(tb[7], ba, "3584");                         \
    b0 = ((const float4*)pB)[0]; b1 = ((const float4*)pB)[1];                     \
    if ((T_) < 174) { pB += 32 * (size_t)HID; }                                   \
    gload16(srcA0, &Ald[PN][(w * 2 + 0) * 512]);                                  \
    gload16(srcA1, &Ald[PN][(w * 2 + 1) * 512]);                                  \
    srcA0 += 32; srcA1 += 32;                                                     \
    asm volatile("s_waitcnt lgkmcnt(0)" ::: "memory");                            \
    __builtin_amdgcn_sched_barrier(0);                                           \
    s16x8 bf[4];                                                                  \
    _Pragma("unroll")                                                             \
    for (int nf = 0; nf < 4; nf++) bf[nf] = cmb(tb[2 * nf], tb[2 * nf + 1]);      \
    _Pragma("unroll")                                                             \
    for (int mf = 0; mf < 4; mf++)                                                \
      _Pragma("unroll")                                                           \
      for (int nf = 0; nf < 4; nf++)                                              \
        acc[mf][nf] = __builtin_amdgcn_mfma_f32_16x16x32_bf16(af[mf], bf[nf], acc[mf][nf], 0, 0, 0); \
  }

  for (int t = 0; t < 176; t += 2) {
    G2_BODY(0, 1, t)
    G2_BODY(1, 0, t + 1)
  }
#undef G2_BODY

  const int* tle = lists + e * NTOK + mt * 256;
  const float* wle = wlists + e * NTOK + mt * 256;
#pragma unroll
  for (int mf = 0; mf < 4; mf++) {
#pragma unroll
    for (int reg = 0; reg < 4; reg++) {
      const int row = wm * 64 + mf * 16 + (lane >> 4) * 4 + reg;
      if (row < lim) {
        const int tok = tle[row];
        const float wt = wle[row];
        float* op = out + (size_t)tok * HID + n0 + wn * 64 + (lane & 15);
#pragma unroll
        for (int nf = 0; nf < 4; nf++)
          atomicAdd(op + nf * 16, acc[mf][nf][reg] * wt);
      }
    }
  }
}

extern "C" void kernel_launch(void* const* d_in, const int* in_sizes, int n_in,
                              void* d_out, int out_size, void* d_ws, size_t ws_size,
                              hipStream_t stream) {
  const float* x  = (const float*)d_in[0];
  const float* wr = (const float*)d_in[1];
  const float* wg = (const float*)d_in[2];
  const float* wu = (const float*)d_in[3];
  const float* wd = (const float*)d_in[4];
  float* out = (float*)d_out;

  // workspace layout
  int* cnt    = (int*)d_ws;                          // 8 ints
  int* offs   = cnt + 8;                             // 9 ints
  int* lists  = cnt + 32;                            // 8*8192 ints
  float* wlists = (float*)(lists + NEXP * NTOK);     // 8*8192 floats
  __hip_bfloat16* xbf  = (__hip_bfloat16*)((char*)d_ws + (1u << 20));            // 8192x2048 bf16 (32 MB)
  __hip_bfloat16* hbuf = (__hip_bfloat16*)((char*)d_ws + (36u << 20));           // 16384x5632 bf16 (~184.6 MB)

  hipMemsetAsync(cnt, 0, 32 * sizeof(int), stream);
  hipMemsetAsync(out, 0, (size_t)NTOK * HID * sizeof(float), stream);

  router_kernel<<<NTOK / 4, 256, 0, stream>>>(x, wr, cnt, lists, wlists, xbf);
  offsets_kernel<<<1, 64, 0, stream>>>(cnt, offs);
  gemm1_kernel<<<NEXP * NT1 * MT_MAX, 512, 0, stream>>>(xbf, wg, wu, cnt, offs, lists, hbuf);
  gemm2_kernel<<<NEXP * NT2 * MT_MAX, 512, 0, stream>>>(hbuf, wd, cnt, offs, lists, wlists, out);
}